// Round 1
// baseline (726.324 us; speedup 1.0000x reference)
//
#include <hip/hip_runtime.h>
#include <hip/hip_cooperative_groups.h>
#include <hip/hip_bf16.h>

namespace cg = cooperative_groups;

#define RS   100            // row stride (floats) of a 97x97 plane (padded for float4 alignment)
#define PLS  9700           // plane stride = 97 rows * RS
#define NP   9409           // 97*97 valid elements per plane
#define LSTR 34             // maxplus LDS row stride: bank=(2k+r)%32 -> worst 2-way (free); 8B-aligned

// ws layout (float offsets) — weights read directly from d_in (fp32)
#define OFF_R   0                          // 4*32 planes (pooled relations, padded/shifted)
#define OFF_A   (OFF_R  + 4*32*PLS)        // 4*16 planes (ft projection)
#define OFF_Bm  (OFF_A  + 4*16*PLS)        // 4*16 planes (rt projection)
#define OFF_F1  (OFF_Bm + 4*16*PLS)        // 4*16 planes (dp step-0 output)
#define OFF_F2  (OFF_F1 + 4*16*PLS)        // 4*16 planes (dp step-1 output)
// total = 384 planes * 9700 * 4 B = 14.9 MB of ws

__device__ __forceinline__ float sigm(float x) { return 1.0f / (1.0f + __expf(-x)); }

// Shared memory overlay: pool phase needs 96x97 floats (37.25 KB);
// maxplus phases need 2 panels of 97*34 floats (26.4 KB). Union = 37.25 KB.
// 4 blocks/CU * 37.25 KB = 149 KB <= 160 KB LDS.
union SMem {
    float pool[96][97];
    struct { float As[97 * LSTR]; float Bs[97 * LSTR]; } mp;
};

// ---------------- max-plus "GEMM" task: F[i][j] = sigmoid(bias + max_k A[i][k]+B[k][j]) ----------------
// Same proven R7 config: 32x32 tile, 2x2/thread. task = bh*16 + tile.
__device__ __forceinline__ void maxplus_task(int task, const float* __restrict__ A,
                                             const float* __restrict__ Bm,
                                             const float* __restrict__ bias,
                                             float* __restrict__ F,
                                             float* __restrict__ As, float* __restrict__ Bs) {
    const int tid = threadIdx.x;
    const int bh = task >> 4;
    const int t4 = task & 15;
    const int h  = bh & 15;
    const int i0 = (t4 & 3) * 32;
    const int j0 = (t4 >> 2) * 32;
    const float* Ab = A  + (size_t)bh * PLS;
    const float* Bb = Bm + (size_t)bh * PLS;

    for (int idx = tid; idx < 32 * 97; idx += 256) {      // A panel, transposed into LDS
        int r = idx / 97, k = idx - r * 97;               // consecutive tid -> consecutive k (coalesced)
        int ii = i0 + r;
        As[k * LSTR + r] = (ii < 97) ? Ab[ii * RS + k] : -1e30f;
    }
    for (int idx = tid; idx < 97 * 32; idx += 256) {      // B panel, direct
        int k = idx >> 5, c = idx & 31;                   // consecutive tid -> consecutive jj (coalesced)
        int jj = j0 + c;
        Bs[k * LSTR + c] = (jj < 97) ? Bb[k * RS + jj] : -1e30f;
    }
    __syncthreads();

    const int ty = tid >> 4, tx = tid & 15;
    float a00 = -1e30f, a01 = -1e30f, a10 = -1e30f, a11 = -1e30f;

#pragma unroll 4
    for (int k = 0; k < 97; ++k) {
        const float2 a2 = *reinterpret_cast<const float2*>(&As[k * LSTR + ty * 2]);  // broadcast in ty-group
        const float2 b2 = *reinterpret_cast<const float2*>(&Bs[k * LSTR + tx * 2]);  // spans all banks
        a00 = fmaxf(a00, a2.x + b2.x);
        a01 = fmaxf(a01, a2.x + b2.y);
        a10 = fmaxf(a10, a2.y + b2.x);
        a11 = fmaxf(a11, a2.y + b2.y);
    }

    const float bb = bias[h];
    float* Fb = F + (size_t)bh * PLS;
    const int col0 = j0 + tx * 2;
    const int row0 = i0 + ty * 2;
    float v[2][2] = {{a00, a01}, {a10, a11}};
#pragma unroll
    for (int r = 0; r < 2; ++r) {
        const int row = row0 + r;
        if (row > 96) continue;
        if (col0 + 1 <= 96) {
            float2 o;
            o.x = sigm(v[r][0] + bb);
            o.y = sigm(v[r][1] + bb);
            *reinterpret_cast<float2*>(&Fb[row * RS + col0]) = o;
        } else if (col0 <= 96) {
            Fb[row * RS + col0] = sigm(v[r][0] + bb);
        }
    }
    __syncthreads();   // LDS reused by next task / phase
}

// ---------------- fused pipeline: pool -> proj0 -> maxplus -> proj1 -> maxplus -> final ----------------
__global__ __launch_bounds__(256, 4) void fused_kernel(
    const float* __restrict__ a,
    const float* __restrict__ W0, const float* __restrict__ b0,
    const float* __restrict__ W1, const float* __restrict__ b1,
    const float* __restrict__ W2, const float* __restrict__ b2,
    float* __restrict__ ws, float* __restrict__ out)
{
    cg::grid_group grid = cg::this_grid();
    __shared__ alignas(16) SMem sm;
    const int tid = threadIdx.x;

    const float* R  = ws + OFF_R;
    float* A  = ws + OFF_A;
    float* Bm = ws + OFF_Bm;
    float* F1 = ws + OFF_F1;
    float* F2 = ws + OFF_F2;

    // ---- phase 1: interval pooling (max & min) + pad -> R planes. 128 tasks (b,ch). ----
    for (int task = blockIdx.x; task < 128; task += gridDim.x) {
        const int b  = task >> 5;
        const int ch = task & 31;
        const int d  = ch & 15;
        const bool isMin = (ch >= 16);
        float (*s)[97] = sm.pool;

        for (int idx = tid; idx < 96 * 96; idx += 256) {
            int i = idx / 96, j = idx - i * 96;
            float v = a[((size_t)(b * 96 + i) * 96 + j) * 16 + d];
            if (isMin) v = -v;
            s[i][j] = (j >= i) ? v : -1e30f;
        }
        __syncthreads();
        if (tid < 96) {              // reverse cummax over i (thread = column j)
            int j = tid; float run = -1e30f;
#pragma unroll 4
            for (int i = 95; i >= 0; --i) { run = fmaxf(run, s[i][j]); s[i][j] = run; }
        }
        __syncthreads();
        if (tid < 96) {              // forward cummax over j (thread = row i)
            int i = tid; float run = -1e30f;
#pragma unroll 4
            for (int j = 0; j < 96; ++j) { run = fmaxf(run, s[i][j]); s[i][j] = run; }
        }
        __syncthreads();
        float* Rp = ws + OFF_R + (size_t)task * PLS;
        for (int idx = tid; idx < 97 * 97; idx += 256) {
            int x = idx / 97, y = idx - x * 97;
            float v = 0.f;
            if (x <= 95 && y >= 1 && x <= y - 1) { v = s[x][y - 1]; if (isMin) v = -v; }
            Rp[x * RS + y] = v;
        }
        __syncthreads();
    }
    grid.sync();

    // ---- phase 2: proj0. A = r@Wf, B = r@Wr. 1184 tasks (37 p-chunks x 32 (b,hpair)). ----
    for (int task = blockIdx.x; task < 37 * 32; task += gridDim.x) {
        const int px = task % 37;
        const int by = task / 37;
        const int b = by >> 3, hp = by & 7;
        const int h0 = hp * 2, h1 = h0 + 1;
        const int p = px * 256 + tid;
        if (p < NP) {
            const int x = p / 97, y = p - x * 97;
            const int off = x * RS + y;
            const float* Rb = R + (size_t)b * 32 * PLS + off;
            float accA0 = 0.f, accA1 = 0.f, accB0 = 0.f, accB1 = 0.f;
#pragma unroll
            for (int d = 0; d < 32; ++d) {
                float rv = Rb[(size_t)d * PLS];
                accA0 += rv * W0[d * 16 + h0];
                accA1 += rv * W0[d * 16 + h1];
                accB0 += rv * W0[(32 + d) * 16 + h0];
                accB1 += rv * W0[(32 + d) * 16 + h1];
            }
            A [(size_t)(b * 16 + h0) * PLS + off] = accA0;
            A [(size_t)(b * 16 + h1) * PLS + off] = accA1;
            Bm[(size_t)(b * 16 + h0) * PLS + off] = accB0;
            Bm[(size_t)(b * 16 + h1) * PLS + off] = accB1;
        }
    }
    grid.sync();

    // ---- phase 3: maxplus step 0 -> F1. 1024 tasks. ----
    for (int task = blockIdx.x; task < 1024; task += gridDim.x)
        maxplus_task(task, A, Bm, b0, F1, sm.mp.As, sm.mp.Bs);
    grid.sync();

    // ---- phase 4: proj1. A = [f1,r]@Wf, B = r@Wr. 1184 tasks. ----
    for (int task = blockIdx.x; task < 37 * 32; task += gridDim.x) {
        const int px = task % 37;
        const int by = task / 37;
        const int b = by >> 3, hp = by & 7;
        const int h0 = hp * 2, h1 = h0 + 1;
        const int p = px * 256 + tid;
        if (p < NP) {
            const int x = p / 97, y = p - x * 97;
            const int off = x * RS + y;
            const float* Rb = R  + (size_t)b * 32 * PLS + off;
            const float* Fb = F1 + (size_t)b * 16 * PLS + off;
            float accA0 = 0.f, accA1 = 0.f, accB0 = 0.f, accB1 = 0.f;
#pragma unroll
            for (int c = 0; c < 16; ++c) {
                float fv = Fb[(size_t)c * PLS];
                accA0 += fv * W1[c * 16 + h0];
                accA1 += fv * W1[c * 16 + h1];
            }
#pragma unroll
            for (int d = 0; d < 32; ++d) {
                float rv = Rb[(size_t)d * PLS];
                accA0 += rv * W1[(16 + d) * 16 + h0];
                accA1 += rv * W1[(16 + d) * 16 + h1];
                accB0 += rv * W1[(48 + d) * 16 + h0];
                accB1 += rv * W1[(48 + d) * 16 + h1];
            }
            A [(size_t)(b * 16 + h0) * PLS + off] = accA0;
            A [(size_t)(b * 16 + h1) * PLS + off] = accA1;
            Bm[(size_t)(b * 16 + h0) * PLS + off] = accB0;
            Bm[(size_t)(b * 16 + h1) * PLS + off] = accB1;
        }
    }
    grid.sync();

    // ---- phase 5: maxplus step 1 -> F2. 1024 tasks. ----
    for (int task = blockIdx.x; task < 1024; task += gridDim.x)
        maxplus_task(task, A, Bm, b1, F2, sm.mp.As, sm.mp.Bs);
    grid.sync();

    // ---- phase 6: final. out = sigmoid([f2,r] @ W2 + b2), cropped. 144 tasks * 256 = 36864 points. ----
    for (int task = blockIdx.x; task < 144; task += gridDim.x) {
        const int p = task * 256 + tid;          // 144*256 == 4*96*96 exactly
        const int oj = p % 96;
        const int t1 = p / 96;
        const int i  = t1 % 96;
        const int b  = t1 / 96;
        const int off = i * RS + (oj + 1);       // j = oj+1 (crop)
        const float* Fb = F2 + (size_t)b * 16 * PLS + off;
        const float* Rb = R  + (size_t)b * 32 * PLS + off;
        float acc[16];
#pragma unroll
        for (int o = 0; o < 16; ++o) acc[o] = b2[o];
#pragma unroll
        for (int c = 0; c < 16; ++c) {
            const float fv = Fb[(size_t)c * PLS];
#pragma unroll
            for (int o = 0; o < 16; ++o) acc[o] += fv * W2[c * 16 + o];
        }
#pragma unroll
        for (int d = 0; d < 32; ++d) {
            const float rv = Rb[(size_t)d * PLS];
#pragma unroll
            for (int o = 0; o < 16; ++o) acc[o] += rv * W2[(16 + d) * 16 + o];
        }
        float4* dst = reinterpret_cast<float4*>(out + (size_t)p * 16);
#pragma unroll
        for (int q = 0; q < 4; ++q) {
            float4 v;
            v.x = sigm(acc[q * 4 + 0]);
            v.y = sigm(acc[q * 4 + 1]);
            v.z = sigm(acc[q * 4 + 2]);
            v.w = sigm(acc[q * 4 + 3]);
            dst[q] = v;
        }
    }
}

extern "C" void kernel_launch(void* const* d_in, const int* in_sizes, int n_in,
                              void* d_out, int out_size, void* d_ws, size_t ws_size,
                              hipStream_t stream) {
    const float* a  = (const float*)d_in[0];
    const float* W0 = (const float*)d_in[1];
    const float* b0 = (const float*)d_in[2];
    const float* W1 = (const float*)d_in[3];
    const float* b1 = (const float*)d_in[4];
    const float* W2 = (const float*)d_in[5];
    const float* b2 = (const float*)d_in[6];
    float* ws  = (float*)d_ws;
    float* out = (float*)d_out;

    // Cooperative launch: grid must be fully co-resident. LDS 37.25 KB/block -> 4 blocks/CU;
    // __launch_bounds__(256,4) caps VGPR<=128 so registers can't reduce that. Validate at runtime.
    static int nb = 0;
    if (nb == 0) {
        int maxb = 0;
        if (hipOccupancyMaxActiveBlocksPerMultiprocessor(&maxb, fused_kernel, 256, 0) != hipSuccess || maxb < 1)
            maxb = 2;                         // conservative fallback (2/CU always fits)
        nb = maxb * 256;                      // 256 CUs on MI355X
        if (nb > 1024) nb = 1024;             // 1024 tasks in the widest phase
    }

    void* args[] = {(void*)&a, (void*)&W0, (void*)&b0, (void*)&W1, (void*)&b1,
                    (void*)&W2, (void*)&b2, (void*)&ws, (void*)&out};
    hipLaunchCooperativeKernel(fused_kernel, dim3(nb), dim3(256), args, 0, stream);
}

// Round 2
// 152.376 us; speedup vs baseline: 4.7667x; 4.7667x over previous
//
#include <hip/hip_runtime.h>

#define RS   100            // row stride (floats) of a 97x97 plane (padded for float4 alignment)
#define PLS  9700           // plane stride = 97 rows * RS
#define NP   9409           // 97*97 valid elements per plane
#define ASTR 34             // maxplus LDS A-panel row stride (proven 2-way-max pattern)
#define BSTR 68             // maxplus LDS B-panel row stride (64 cols + pad, 16B-aligned rows)

// ws layout (float offsets) — weights read directly from d_in (fp32)
#define OFF_R   0                           // 4*32 planes (pooled relations, padded/shifted)
#define OFF_A   (OFF_R   + 4*32*PLS)        // 4*16 planes (ft projection; reused for step-1 A)
#define OFF_Bm  (OFF_A   + 4*16*PLS)        // 4*16 planes (step-0 rt projection)
#define OFF_F1  (OFF_Bm  + 4*16*PLS)        // 4*16 planes (dp step-0 output)
#define OFF_F2  (OFF_F1  + 4*16*PLS)        // 4*16 planes (dp step-1 output)
#define OFF_A1r (OFF_F2  + 4*16*PLS)        // 4*16 planes (r-part of step-1 ft projection)
#define OFF_B1  (OFF_A1r + 4*16*PLS)        // 4*16 planes (step-1 rt projection)
// total = 512 planes * 9700 * 4 B = 19.9 MB of ws

__device__ __forceinline__ float sigm(float x) { return 1.0f / (1.0f + __expf(-x)); }

// ---------------- interval pooling (max & min) + pad -> R planes (unchanged, proven) ----------------
__global__ __launch_bounds__(256) void pool_kernel(const float* __restrict__ a, float* __restrict__ R) {
    __shared__ float s[96][97];   // +1 pad: scans hit distinct banks both directions
    const int tid = threadIdx.x;
    const int b  = blockIdx.x >> 5;
    const int ch = blockIdx.x & 31;
    const int d  = ch & 15;
    const bool isMin = (ch >= 16);

    for (int idx = tid; idx < 96 * 96; idx += 256) {
        int i = idx / 96, j = idx - i * 96;
        float v = a[((size_t)(b * 96 + i) * 96 + j) * 16 + d];
        if (isMin) v = -v;
        s[i][j] = (j >= i) ? v : -1e30f;
    }
    __syncthreads();
    if (tid < 96) {              // reverse cummax over i (thread = column j)
        int j = tid; float run = -1e30f;
#pragma unroll 4
        for (int i = 95; i >= 0; --i) { run = fmaxf(run, s[i][j]); s[i][j] = run; }
    }
    __syncthreads();
    if (tid < 96) {              // forward cummax over j (thread = row i)
        int i = tid; float run = -1e30f;
#pragma unroll 4
        for (int j = 0; j < 96; ++j) { run = fmaxf(run, s[i][j]); s[i][j] = run; }
    }
    __syncthreads();
    float* Rp = R + (size_t)blockIdx.x * PLS;
    for (int idx = tid; idx < 97 * 97; idx += 256) {
        int x = idx / 97, y = idx - x * 97;
        float v = 0.f;
        if (x <= 95 && y >= 1 && x <= y - 1) { v = s[x][y - 1]; if (isMin) v = -v; }
        Rp[x * RS + y] = v;
    }
}

// ---------------- projections that depend only on R: A0=r@W0f, B0=r@W0r, A1r=r@W1f_r, B1=r@W1r ----------------
// One R read feeds 8 accumulators (2 h-channels x 4 weight sets). grid (37, 32): blockIdx.y = b*8 + hpair.
__global__ __launch_bounds__(256) void projA_kernel(const float* __restrict__ R,
                                                    const float* __restrict__ W0, const float* __restrict__ W1,
                                                    float* __restrict__ A0, float* __restrict__ B0,
                                                    float* __restrict__ A1r, float* __restrict__ B1) {
    const int by = blockIdx.y, b = by >> 3, hp = by & 7;
    const int h0 = hp * 2, h1 = h0 + 1;
    const int p = blockIdx.x * 256 + threadIdx.x;
    if (p >= NP) return;
    const int x = p / 97, y = p - x * 97;
    const int off = x * RS + y;
    const float* Rb = R + (size_t)b * 32 * PLS + off;
    float aA00 = 0.f, aA01 = 0.f, aB00 = 0.f, aB01 = 0.f;
    float aA10 = 0.f, aA11 = 0.f, aB10 = 0.f, aB11 = 0.f;
#pragma unroll
    for (int d = 0; d < 32; ++d) {
        const float rv = Rb[(size_t)d * PLS];
        aA00 += rv * W0[d * 16 + h0];
        aA01 += rv * W0[d * 16 + h1];
        aB00 += rv * W0[(32 + d) * 16 + h0];
        aB01 += rv * W0[(32 + d) * 16 + h1];
        aA10 += rv * W1[(16 + d) * 16 + h0];
        aA11 += rv * W1[(16 + d) * 16 + h1];
        aB10 += rv * W1[(48 + d) * 16 + h0];
        aB11 += rv * W1[(48 + d) * 16 + h1];
    }
    const size_t o0 = (size_t)(b * 16 + h0) * PLS + off;
    const size_t o1 = (size_t)(b * 16 + h1) * PLS + off;
    A0 [o0] = aA00;  A0 [o1] = aA01;
    B0 [o0] = aB00;  B0 [o1] = aB01;
    A1r[o0] = aA10;  A1r[o1] = aA11;
    B1 [o0] = aB10;  B1 [o1] = aB11;
}

// ---------------- light critical-path projection: A1 = A1r + F1 @ W1[0:16] ----------------
__global__ __launch_bounds__(256) void projF_kernel(const float* __restrict__ F1, const float* __restrict__ A1r,
                                                    const float* __restrict__ W1, float* __restrict__ A) {
    const int by = blockIdx.y, b = by >> 3, hp = by & 7;
    const int h0 = hp * 2, h1 = h0 + 1;
    const int p = blockIdx.x * 256 + threadIdx.x;
    if (p >= NP) return;
    const int x = p / 97, y = p - x * 97;
    const int off = x * RS + y;
    const float* Fb = F1 + (size_t)b * 16 * PLS + off;
    const size_t o0 = (size_t)(b * 16 + h0) * PLS + off;
    const size_t o1 = (size_t)(b * 16 + h1) * PLS + off;
    float a0 = A1r[o0], a1 = A1r[o1];
#pragma unroll
    for (int c = 0; c < 16; ++c) {
        const float fv = Fb[(size_t)c * PLS];
        a0 += fv * W1[c * 16 + h0];
        a1 += fv * W1[c * 16 + h1];
    }
    A[o0] = a0;
    A[o1] = a1;
}

// ---------------- max-plus "GEMM": F[i][j] = sigmoid(bias + max_k A[i][k]+B[k][j]) ----------------
// v2: 32i x 64j tile, 2x4/thread. B side read as ds_read_b128 (2.5 B LDS per output-k vs 4 B before).
// grid (8, 64): blockIdx.x = (j0/64)*4 + i0/32; blockIdx.y = bh. 512 blocks, LDS 39.6 KB -> 4/CU cap.
__global__ __launch_bounds__(256) void maxplus_kernel(const float* __restrict__ A, const float* __restrict__ Bm,
                                                      const float* __restrict__ bias, float* __restrict__ F) {
    __shared__ alignas(16) float As[97 * ASTR];  // As[k][i-local] (transposed), 32 i-rows
    __shared__ alignas(16) float Bs[97 * BSTR];  // Bs[k][j-local], 64 j-cols
    const int tid = threadIdx.x;
    const int bh = blockIdx.y;
    const int h  = bh & 15;
    const int i0 = (blockIdx.x & 3) * 32;
    const int j0 = (blockIdx.x >> 2) * 64;
    const float* Ab = A  + (size_t)bh * PLS;
    const float* Bb = Bm + (size_t)bh * PLS;

    for (int idx = tid; idx < 32 * 97; idx += 256) {      // A panel, transposed into LDS
        int r = idx / 97, k = idx - r * 97;               // consecutive tid -> consecutive k (coalesced)
        int ii = i0 + r;
        As[k * ASTR + r] = (ii <= 96) ? Ab[ii * RS + k] : -1e30f;
    }
    for (int idx = tid; idx < 97 * 16; idx += 256) {      // B panel, float4 stage (conflict-free writes)
        int k = idx >> 4, q = idx & 15;
        int jj = j0 + q * 4;
        float4 v;
        if (jj + 3 <= 96) {
            v = *reinterpret_cast<const float4*>(&Bb[k * RS + jj]);   // (100k+jj)%4==0 -> 16B aligned
        } else {
            v.x = (jj     <= 96) ? Bb[k * RS + jj]     : -1e30f;
            v.y = (jj + 1 <= 96) ? Bb[k * RS + jj + 1] : -1e30f;
            v.z = (jj + 2 <= 96) ? Bb[k * RS + jj + 2] : -1e30f;
            v.w = -1e30f;
        }
        *reinterpret_cast<float4*>(&Bs[k * BSTR + q * 4]) = v;
    }
    __syncthreads();

    const int ty = tid >> 4, tx = tid & 15;               // ty -> 2 i-rows, tx -> 4 j-cols
    float acc[2][4];
#pragma unroll
    for (int r = 0; r < 2; ++r)
#pragma unroll
        for (int c = 0; c < 4; ++c) acc[r][c] = -1e30f;

#pragma unroll 4
    for (int k = 0; k < 97; ++k) {
        const float2 a2 = *reinterpret_cast<const float2*>(&As[k * ASTR + ty * 2]);  // broadcast in ty-group
        const float4 b4 = *reinterpret_cast<const float4*>(&Bs[k * BSTR + tx * 4]);  // b128, <=2-way
        acc[0][0] = fmaxf(acc[0][0], a2.x + b4.x);
        acc[0][1] = fmaxf(acc[0][1], a2.x + b4.y);
        acc[0][2] = fmaxf(acc[0][2], a2.x + b4.z);
        acc[0][3] = fmaxf(acc[0][3], a2.x + b4.w);
        acc[1][0] = fmaxf(acc[1][0], a2.y + b4.x);
        acc[1][1] = fmaxf(acc[1][1], a2.y + b4.y);
        acc[1][2] = fmaxf(acc[1][2], a2.y + b4.z);
        acc[1][3] = fmaxf(acc[1][3], a2.y + b4.w);
    }

    const float bb = bias[h];
    float* Fb = F + (size_t)bh * PLS;
    const int row0 = i0 + ty * 2;
    const int col0 = j0 + tx * 4;
#pragma unroll
    for (int r = 0; r < 2; ++r) {
        const int row = row0 + r;
        if (row > 96) continue;
        if (col0 + 3 <= 96) {
            float4 o;
            o.x = sigm(acc[r][0] + bb);
            o.y = sigm(acc[r][1] + bb);
            o.z = sigm(acc[r][2] + bb);
            o.w = sigm(acc[r][3] + bb);
            *reinterpret_cast<float4*>(&Fb[row * RS + col0]) = o;    // (100row+col0)%4==0
        } else {
#pragma unroll
            for (int c = 0; c < 4; ++c) {
                const int col = col0 + c;
                if (col <= 96) Fb[row * RS + col] = sigm(acc[r][c] + bb);
            }
        }
    }
}

// ---------------- final: out = sigmoid([f2,r] @ W2 + b2), cropped [:, :-1, 1:] ----------------
// v2: thread = (point, output-quad). 576 blocks (2.25/CU) fixes the 0.56/CU latency exposure.
__global__ __launch_bounds__(256) void final_kernel(const float* __restrict__ R, const float* __restrict__ F2,
                                                    const float* __restrict__ W, const float* __restrict__ bias,
                                                    float* __restrict__ out) {
    const int g = blockIdx.x * 256 + threadIdx.x;         // 576*256 == 4*96*96*4 exactly
    const int p  = g >> 2;                                // point index
    const int oq = g & 3;                                 // output quad (4 floats)
    const int oj = p % 96;
    const int t1 = p / 96;
    const int i  = t1 % 96;
    const int b  = t1 / 96;
    const int off = i * RS + (oj + 1);                    // j = oj+1 (crop)
    const float* Fb = F2 + (size_t)b * 16 * PLS + off;
    const float* Rb = R  + (size_t)b * 32 * PLS + off;
    float acc[4];
#pragma unroll
    for (int m = 0; m < 4; ++m) acc[m] = bias[oq * 4 + m];
#pragma unroll
    for (int c = 0; c < 16; ++c) {
        const float fv = Fb[(size_t)c * PLS];
#pragma unroll
        for (int m = 0; m < 4; ++m) acc[m] += fv * W[c * 16 + oq * 4 + m];
    }
#pragma unroll
    for (int d = 0; d < 32; ++d) {
        const float rv = Rb[(size_t)d * PLS];
#pragma unroll
        for (int m = 0; m < 4; ++m) acc[m] += rv * W[(16 + d) * 16 + oq * 4 + m];
    }
    float4 v;
    v.x = sigm(acc[0]);
    v.y = sigm(acc[1]);
    v.z = sigm(acc[2]);
    v.w = sigm(acc[3]);
    *reinterpret_cast<float4*>(out + (size_t)p * 16 + oq * 4) = v;
}

extern "C" void kernel_launch(void* const* d_in, const int* in_sizes, int n_in,
                              void* d_out, int out_size, void* d_ws, size_t ws_size,
                              hipStream_t stream) {
    const float* a  = (const float*)d_in[0];
    const float* W0 = (const float*)d_in[1];
    const float* b0 = (const float*)d_in[2];
    const float* W1 = (const float*)d_in[3];
    const float* b1 = (const float*)d_in[4];
    const float* W2 = (const float*)d_in[5];
    const float* b2 = (const float*)d_in[6];
    float* ws  = (float*)d_ws;
    float* out = (float*)d_out;

    hipLaunchKernelGGL(pool_kernel, dim3(128), dim3(256), 0, stream, a, ws + OFF_R);
    hipLaunchKernelGGL(projA_kernel, dim3(37, 32), dim3(256), 0, stream,
                       ws + OFF_R, W0, W1, ws + OFF_A, ws + OFF_Bm, ws + OFF_A1r, ws + OFF_B1);
    hipLaunchKernelGGL(maxplus_kernel, dim3(8, 64), dim3(256), 0, stream,
                       ws + OFF_A, ws + OFF_Bm, b0, ws + OFF_F1);
    hipLaunchKernelGGL(projF_kernel, dim3(37, 32), dim3(256), 0, stream,
                       ws + OFF_F1, ws + OFF_A1r, W1, ws + OFF_A);
    hipLaunchKernelGGL(maxplus_kernel, dim3(8, 64), dim3(256), 0, stream,
                       ws + OFF_A, ws + OFF_B1, b1, ws + OFF_F2);
    hipLaunchKernelGGL(final_kernel, dim3(576), dim3(256), 0, stream,
                       ws + OFF_R, ws + OFF_F2, W2, b2, out);
}

// Round 3
// 150.361 us; speedup vs baseline: 4.8305x; 1.0134x over previous
//
#include <hip/hip_runtime.h>

#define RS   100            // row stride (floats) of a 97x97 plane
#define PLS  9700           // plane stride = 97 rows * RS
#define NP   9409           // 97*97 valid elements per plane

// ws layout (float offsets)
#define OFF_R   0                           // 4*32 planes (pooled relations)
#define OFF_A   (OFF_R   + 4*32*PLS)        // 4*16 planes: A0 = r@W0f
#define OFF_Bm  (OFF_A   + 4*16*PLS)        // 4*16 planes: B0 = r@W0r
#define OFF_F1  (OFF_Bm  + 4*16*PLS)        // 4*16 planes: A1 (mpA output; F1 itself never materialized)
#define OFF_F2  (OFF_F1  + 4*16*PLS)        // unused (layout kept)
#define OFF_A1r (OFF_F2  + 4*16*PLS)        // 4*16 planes: r-part of step-1 ft projection
#define OFF_B1  (OFF_A1r + 4*16*PLS)        // 4*16 planes: B1 = r@W1r

// mp_fused LDS geometry
#define HSTR  328   // h-stride (words) in As/Bs: (328%32)=8 -> b128 reads max 2-way conflict (free)
#define KSTR  20    // k-stride (words): keeps b128 16B-aligned, spreads banks
#define FSTR  17    // inner stride of Fs[16][16][17] (conflict-breaking pad)

__device__ __forceinline__ float sigm(float x) { return 1.0f / (1.0f + __expf(-x)); }

// ---------------- interval pooling (max & min) + pad -> R planes (unchanged, proven) ----------------
__global__ __launch_bounds__(256) void pool_kernel(const float* __restrict__ a, float* __restrict__ R) {
    __shared__ float s[96][97];
    const int tid = threadIdx.x;
    const int b  = blockIdx.x >> 5;
    const int ch = blockIdx.x & 31;
    const int d  = ch & 15;
    const bool isMin = (ch >= 16);

    for (int idx = tid; idx < 96 * 96; idx += 256) {
        int i = idx / 96, j = idx - i * 96;
        float v = a[((size_t)(b * 96 + i) * 96 + j) * 16 + d];
        if (isMin) v = -v;
        s[i][j] = (j >= i) ? v : -1e30f;
    }
    __syncthreads();
    if (tid < 96) {              // reverse cummax over i (thread = column j)
        int j = tid; float run = -1e30f;
#pragma unroll 4
        for (int i = 95; i >= 0; --i) { run = fmaxf(run, s[i][j]); s[i][j] = run; }
    }
    __syncthreads();
    if (tid < 96) {              // forward cummax over j (thread = row i)
        int i = tid; float run = -1e30f;
#pragma unroll 4
        for (int j = 0; j < 96; ++j) { run = fmaxf(run, s[i][j]); s[i][j] = run; }
    }
    __syncthreads();
    float* Rp = R + (size_t)blockIdx.x * PLS;
    for (int idx = tid; idx < 97 * 97; idx += 256) {
        int x = idx / 97, y = idx - x * 97;
        float v = 0.f;
        if (x <= 95 && y >= 1 && x <= y - 1) { v = s[x][y - 1]; if (isMin) v = -v; }
        Rp[x * RS + y] = v;
    }
}

// ---------------- projections that depend only on R (unchanged, proven) ----------------
__global__ __launch_bounds__(256) void projA_kernel(const float* __restrict__ R,
                                                    const float* __restrict__ W0, const float* __restrict__ W1,
                                                    float* __restrict__ A0, float* __restrict__ B0,
                                                    float* __restrict__ A1r, float* __restrict__ B1) {
    const int by = blockIdx.y, b = by >> 3, hp = by & 7;
    const int h0 = hp * 2, h1 = h0 + 1;
    const int p = blockIdx.x * 256 + threadIdx.x;
    if (p >= NP) return;
    const int x = p / 97, y = p - x * 97;
    const int off = x * RS + y;
    const float* Rb = R + (size_t)b * 32 * PLS + off;
    float aA00 = 0.f, aA01 = 0.f, aB00 = 0.f, aB01 = 0.f;
    float aA10 = 0.f, aA11 = 0.f, aB10 = 0.f, aB11 = 0.f;
#pragma unroll
    for (int d = 0; d < 32; ++d) {
        const float rv = Rb[(size_t)d * PLS];
        aA00 += rv * W0[d * 16 + h0];
        aA01 += rv * W0[d * 16 + h1];
        aB00 += rv * W0[(32 + d) * 16 + h0];
        aB01 += rv * W0[(32 + d) * 16 + h1];
        aA10 += rv * W1[(16 + d) * 16 + h0];
        aA11 += rv * W1[(16 + d) * 16 + h1];
        aB10 += rv * W1[(48 + d) * 16 + h0];
        aB11 += rv * W1[(48 + d) * 16 + h1];
    }
    const size_t o0 = (size_t)(b * 16 + h0) * PLS + off;
    const size_t o1 = (size_t)(b * 16 + h1) * PLS + off;
    A0 [o0] = aA00;  A0 [o1] = aA01;
    B0 [o0] = aB00;  B0 [o1] = aB01;
    A1r[o0] = aA10;  A1r[o1] = aA11;
    B1 [o0] = aB10;  B1 [o1] = aB11;
}

// ---------------- fused all-h maxplus + pointwise epilogue ----------------
// Block = (b, 16x16 (i,j) tile), ALL 16 h channels. thread: h = tid>>4, q = tid&15 -> 4x4 sub-tile.
// Maxplus F[h][i][j] = sigm(bias[h] + max_k A[h][i][k]+B[h][k][j]) kept entirely in LDS, then:
//   LAST=false: A1[h'] = A1r[h'] + sum_c F1[c]*W1[c][h']      (projF fused; Out = A1 planes)
//   LAST=true : out    = sigm(sum_c F2[c]*W2[c][:] + sum_d R[d]*W2[16+d][:] + b2)  (final fused)
template<bool LAST>
__global__ __launch_bounds__(256) void mp_fused(
    const float* __restrict__ A, const float* __restrict__ B,
    const float* __restrict__ biasv,          // b0 / b1
    const float* __restrict__ Wx,             // LAST ? W2 (48x16) : W1 (rows 0..15 used)
    const float* __restrict__ Aux,            // LAST ? R base : A1r base
    const float* __restrict__ bias2,          // LAST ? b2 : unused
    float* __restrict__ Out)                  // LAST ? out : A1 planes
{
    __shared__ float As[16 * HSTR];           // As[h][k][i] (transposed), one 16-k chunk
    __shared__ float Bs[16 * HSTR];           // Bs[h][k][j]
    __shared__ float Fs[16 * 16 * FSTR];      // F tile, all 16 channels
    __shared__ float Ws[768];                 // staged weights (256 or 768 used)

    const int tid = threadIdx.x;
    const int b  = blockIdx.y;
    const int ti = blockIdx.x / 7, tj = blockIdx.x % 7;
    const int i0 = ti * 16, j0 = tj * 16;
    const int h  = tid >> 4, q = tid & 15;
    const int iq = q >> 2, jq = q & 3;

    {   // stage weights (consumed only after later barriers)
        const int nw = LAST ? 768 : 256;
        for (int s = tid; s < nw; s += 256) Ws[s] = Wx[s];
    }

    const float* Ab = A + (size_t)(b * 16 + h) * PLS;
    const float* Bb = B + (size_t)(b * 16 + h) * PLS;

    float4 Ar[4], Br[4];                      // reg double-buffer for one 16-k chunk

    // ---- chunk load: 16h x 16i x 16k (A, transposed on store) and 16h x 16k x 16j (B) ----
    auto load_chunk = [&](int kc) {
#pragma unroll
        for (int t = 0; t < 4; ++t) {
            const int s  = t * 256 + tid;
            const int h2 = s >> 6;            // plane channel
            const int m2 = (s >> 2) & 15;     // A: i index | B: k index
            const int q2 = s & 3;             // A: k-quad  | B: j-quad
            const float* Ap = A + (size_t)(b * 16 + h2) * PLS;
            const int row = i0 + m2;
            if (row <= 96) Ar[t] = *reinterpret_cast<const float4*>(&Ap[row * RS + kc + q2 * 4]);
            else           Ar[t] = make_float4(-1e30f, -1e30f, -1e30f, -1e30f);
            const float* Bp = B + (size_t)(b * 16 + h2) * PLS;
            const int colq = j0 + q2 * 4;
            if (colq + 3 <= 96) {
                Br[t] = *reinterpret_cast<const float4*>(&Bp[(kc + m2) * RS + colq]);
            } else {
                float v[4];
#pragma unroll
                for (int e = 0; e < 4; ++e) {
                    const int col = colq + e;
                    v[e] = (col <= 96) ? Bp[(kc + m2) * RS + col] : -1e30f;
                }
                Br[t] = make_float4(v[0], v[1], v[2], v[3]);
            }
        }
    };
    auto store_chunk = [&]() {
#pragma unroll
        for (int t = 0; t < 4; ++t) {
            const int s  = t * 256 + tid;
            const int h2 = s >> 6;
            const int m2 = (s >> 2) & 15;
            const int q2 = s & 3;
            float* as = &As[h2 * HSTR + m2];              // A transposed: [h][k][i]
            as[(q2 * 4 + 0) * KSTR] = Ar[t].x;
            as[(q2 * 4 + 1) * KSTR] = Ar[t].y;
            as[(q2 * 4 + 2) * KSTR] = Ar[t].z;
            as[(q2 * 4 + 3) * KSTR] = Ar[t].w;
            *reinterpret_cast<float4*>(&Bs[h2 * HSTR + m2 * KSTR + q2 * 4]) = Br[t];  // B direct: [h][k][j]
        }
    };

    float acc[4][4];
#pragma unroll
    for (int r = 0; r < 4; ++r)
#pragma unroll
        for (int c = 0; c < 4; ++c) acc[r][c] = -1e30f;

    auto compute_k = [&](int k) {
        const float4 av = *reinterpret_cast<const float4*>(&As[h * HSTR + k * KSTR + iq * 4]);
        const float4 bv = *reinterpret_cast<const float4*>(&Bs[h * HSTR + k * KSTR + jq * 4]);
        const float aa[4] = {av.x, av.y, av.z, av.w};
        const float bb[4] = {bv.x, bv.y, bv.z, bv.w};
#pragma unroll
        for (int r = 0; r < 4; ++r)
#pragma unroll
            for (int c = 0; c < 4; ++c) acc[r][c] = fmaxf(acc[r][c], aa[r] + bb[c]);
    };

    // ---- main loop: 6 chunks of 16 k, reg-double-buffered; then edge k=96 ----
    load_chunk(0);
    store_chunk();
    __syncthreads();
    for (int c = 0; c < 6; ++c) {
        if (c < 5) load_chunk((c + 1) * 16);  // issue next-chunk loads before compute (hide latency)
#pragma unroll
        for (int k = 0; k < 16; ++k) compute_k(k);
        __syncthreads();                      // LDS reads done
        if (c < 5) { store_chunk(); __syncthreads(); }
    }
    // edge column k = 96 (reuse k-slot 0 of both panels)
    As[h * HSTR + q] = (i0 + q <= 96) ? Ab[(i0 + q) * RS + 96] : -1e30f;
    Bs[h * HSTR + q] = (j0 + q <= 96) ? Bb[96 * RS + (j0 + q)] : -1e30f;
    __syncthreads();
    compute_k(0);

    // ---- F tile (all 16 channels) -> LDS ----
    const float bbia = biasv[h];
#pragma unroll
    for (int r = 0; r < 4; ++r)
#pragma unroll
        for (int c = 0; c < 4; ++c)
            Fs[h * (16 * FSTR) + (iq * 4 + r) * FSTR + (jq * 4 + c)] = sigm(acc[r][c] + bbia);
    __syncthreads();

    if (!LAST) {
        // ---- projF fused: A1[h] = A1r[h] + sum_c F1[c]*W1[c][h], per tile point ----
        const float* Axr = Aux + (size_t)(b * 16 + h) * PLS;
        float* Ob = Out + (size_t)(b * 16 + h) * PLS;
        const int ybase = j0 + jq * 4;
        const bool fullq = (ybase + 3 <= 96);
#pragma unroll
        for (int r = 0; r < 4; ++r) {
            const int x = i0 + iq * 4 + r;
            if (x > 96) continue;
            float o4[4];
            if (fullq) {
                const float4 t4 = *reinterpret_cast<const float4*>(&Axr[x * RS + ybase]);
                o4[0] = t4.x; o4[1] = t4.y; o4[2] = t4.z; o4[3] = t4.w;
            } else {
#pragma unroll
                for (int e = 0; e < 4; ++e) o4[e] = (ybase + e <= 96) ? Axr[x * RS + ybase + e] : 0.f;
            }
#pragma unroll
            for (int c16 = 0; c16 < 16; ++c16) {
                const float w = Ws[c16 * 16 + h];
                const float* fr = &Fs[c16 * (16 * FSTR) + (iq * 4 + r) * FSTR + jq * 4];
                o4[0] += fr[0] * w; o4[1] += fr[1] * w; o4[2] += fr[2] * w; o4[3] += fr[3] * w;
            }
            if (fullq) {
                *reinterpret_cast<float4*>(&Ob[x * RS + ybase]) = make_float4(o4[0], o4[1], o4[2], o4[3]);
            } else {
#pragma unroll
                for (int e = 0; e < 4; ++e) if (ybase + e <= 96) Ob[x * RS + ybase + e] = o4[e];
            }
        }
    } else {
        // ---- final fused: thread = tile point; out = sigm([F2,r]@W2 + b2), cropped ----
        const int pi = tid >> 4, pj = tid & 15;
        const int x = i0 + pi, y = j0 + pj;
        if (x <= 95 && y >= 1 && y <= 96) {
            const float* Rb = Aux + (size_t)b * 32 * PLS + x * RS + y;
            float o[16];
#pragma unroll
            for (int oo = 0; oo < 16; ++oo) o[oo] = bias2[oo];
#pragma unroll
            for (int c = 0; c < 16; ++c) {
                const float fv = Fs[c * (16 * FSTR) + pi * FSTR + pj];
#pragma unroll
                for (int oo = 0; oo < 16; ++oo) o[oo] += fv * Ws[c * 16 + oo];
            }
#pragma unroll
            for (int d = 0; d < 32; ++d) {
                const float rv = Rb[(size_t)d * PLS];
#pragma unroll
                for (int oo = 0; oo < 16; ++oo) o[oo] += rv * Ws[(16 + d) * 16 + oo];
            }
            float* dst = Out + ((size_t)((b * 96 + x) * 96) + (y - 1)) * 16;
#pragma unroll
            for (int qd = 0; qd < 4; ++qd) {
                float4 v;
                v.x = sigm(o[qd * 4 + 0]);
                v.y = sigm(o[qd * 4 + 1]);
                v.z = sigm(o[qd * 4 + 2]);
                v.w = sigm(o[qd * 4 + 3]);
                *reinterpret_cast<float4*>(&dst[qd * 4]) = v;
            }
        }
    }
}

extern "C" void kernel_launch(void* const* d_in, const int* in_sizes, int n_in,
                              void* d_out, int out_size, void* d_ws, size_t ws_size,
                              hipStream_t stream) {
    const float* a  = (const float*)d_in[0];
    const float* W0 = (const float*)d_in[1];
    const float* b0 = (const float*)d_in[2];
    const float* W1 = (const float*)d_in[3];
    const float* b1 = (const float*)d_in[4];
    const float* W2 = (const float*)d_in[5];
    const float* b2 = (const float*)d_in[6];
    float* ws  = (float*)d_ws;
    float* out = (float*)d_out;

    hipLaunchKernelGGL(pool_kernel, dim3(128), dim3(256), 0, stream, a, ws + OFF_R);
    hipLaunchKernelGGL(projA_kernel, dim3(37, 32), dim3(256), 0, stream,
                       ws + OFF_R, W0, W1, ws + OFF_A, ws + OFF_Bm, ws + OFF_A1r, ws + OFF_B1);
    hipLaunchKernelGGL((mp_fused<false>), dim3(49, 4), dim3(256), 0, stream,
                       ws + OFF_A, ws + OFF_Bm, b0, W1, ws + OFF_A1r, b0, ws + OFF_F1);
    hipLaunchKernelGGL((mp_fused<true>), dim3(49, 4), dim3(256), 0, stream,
                       ws + OFF_F1, ws + OFF_B1, b1, W2, ws + OFF_R, b2, out);
}